// Round 5
// baseline (836.949 us; speedup 1.0000x reference)
//
#include <hip/hip_runtime.h>
#include <hip/hip_fp16.h>

#define N_NODES 100000
#define N_EDGES 1600000
#define F_IN 128
#define OUT 32
#define PERIODS 12

// ---------------- prep: M = W @ L_top, cc = b @ L_top + lb, probs = softmax(att)
__global__ void k_prep(const float* __restrict__ Wz, const float* __restrict__ bz,
                       const float* __restrict__ Lz, const float* __restrict__ lbz,
                       const float* __restrict__ Wh, const float* __restrict__ bh,
                       const float* __restrict__ Lh, const float* __restrict__ lbh,
                       const float* __restrict__ att,
                       float* __restrict__ M, float* __restrict__ cc,
                       float* __restrict__ probs) {
    int t = threadIdx.x;
    // M layout: [128][64], c<32 -> Mz column c, c>=32 -> Mh column c-32
    for (int idx = t; idx < F_IN * 64; idx += 256) {
        int f = idx >> 6, c = idx & 63;
        const float* W = (c < 32) ? Wz : Wh;
        const float* L = (c < 32) ? Lz : Lh;
        int cj = c & 31;
        float s = 0.f;
        #pragma unroll 8
        for (int j = 0; j < 32; ++j) s += W[f * 32 + j] * L[j * 32 + cj];
        M[idx] = s;
    }
    if (t < 64) {
        int c = t & 31;
        const float* b  = (t < 32) ? bz : bh;
        const float* L  = (t < 32) ? Lz : Lh;
        const float* lb = (t < 32) ? lbz : lbh;
        float s = lb[c];
        for (int j = 0; j < 32; ++j) s += b[j] * L[j * 32 + c];
        cc[t] = s;
    }
    if (t == 0) {
        float m = att[0];
        for (int p = 1; p < PERIODS; ++p) m = fmaxf(m, att[p]);
        float e[PERIODS]; float sum = 0.f;
        for (int p = 0; p < PERIODS; ++p) { e[p] = expf(att[p] - m); sum += e[p]; }
        for (int p = 0; p < PERIODS; ++p) probs[p] = e[p] / sum;
    }
}

// ---------------- in-degree count (targets = edge_index[1], int32 on device)
__global__ void k_count(const int* __restrict__ ei, int* __restrict__ cnt) {
    int e = blockIdx.x * 256 + threadIdx.x;
    if (e < N_EDGES) {
        int c = ei[N_EDGES + e];
        if ((unsigned)c < N_NODES) atomicAdd(&cnt[c], 1);
    }
}

// ---------------- dis = rsqrt(indeg + 1)
__global__ void k_dis(const int* __restrict__ cnt, float* __restrict__ dis) {
    int i = blockIdx.x * 256 + threadIdx.x;
    if (i < N_NODES) dis[i] = rsqrtf((float)(cnt[i] + 1));
}

// ---------------- 3-kernel exclusive scan of cnt -> rp
__global__ void k_scan1(const int* __restrict__ cnt, int* __restrict__ rp,
                        int* __restrict__ partials) {
    __shared__ int s[256];
    int t = threadIdx.x;
    int i = blockIdx.x * 256 + t;
    int v = (i < N_NODES) ? cnt[i] : 0;
    s[t] = v;
    __syncthreads();
    for (int off = 1; off < 256; off <<= 1) {
        int y = (t >= off) ? s[t - off] : 0;
        __syncthreads();
        s[t] += y;
        __syncthreads();
    }
    if (i < N_NODES) rp[i] = s[t] - v;
    if (t == 255) partials[blockIdx.x] = s[255];
}

__global__ void k_scan2(int* __restrict__ partials, int np) {
    __shared__ int s[512];
    int t = threadIdx.x;
    int v = (t < np) ? partials[t] : 0;
    s[t] = v;
    __syncthreads();
    for (int off = 1; off < 512; off <<= 1) {
        int y = (t >= off) ? s[t - off] : 0;
        __syncthreads();
        s[t] += y;
        __syncthreads();
    }
    if (t < np) partials[t] = s[t] - v;
}

__global__ void k_scan3(int* __restrict__ rp, const int* __restrict__ partials) {
    int i = blockIdx.x * 256 + threadIdx.x;
    if (i < N_NODES) rp[i] += partials[blockIdx.x];
    if (i == 0) rp[N_NODES] = N_EDGES;
}

// ---------------- CSR fill (consumes cnt as the cursor via atomicSub)
__global__ void k_fill(const int* __restrict__ ei, const int* __restrict__ rp,
                       int* __restrict__ cnt, int* __restrict__ srcIdx) {
    int e = blockIdx.x * 256 + threadIdx.x;
    if (e < N_EDGES) {
        int c = ei[N_EDGES + e];
        int r = ei[e];
        if ((unsigned)c < N_NODES) {
            int pos = rp[c] + atomicSub(&cnt[c], 1) - 1;
            srcIdx[pos] = r;
        }
    }
}

// ---------------- projection v4: x from global (L1-broadcast), M from LDS, VALU-bound
// block=256 (4 waves), 32 nodes/block; lane: node = lane>>3, c-octet = lane&7.
__global__ __launch_bounds__(256, 3) void k_proj4(const float* __restrict__ x,
                                                  const float* __restrict__ M,
                                                  __half* __restrict__ U) {
    __shared__ float sM[F_IN * 64];        // 32 KB
    int t = threadIdx.x;

    {   // stage M once (2048 float4)
        const float4* Mv = reinterpret_cast<const float4*>(M);
        float4* sMv = reinterpret_cast<float4*>(sM);
        #pragma unroll
        for (int i = 0; i < 8; ++i) sMv[t + 256 * i] = Mv[t + 256 * i];
    }
    __syncthreads();

    int lane = t & 63;
    int wv = t >> 6;
    int node = blockIdx.x * 32 + wv * 8 + (lane >> 3);
    int co = lane & 7;                     // c-octet: columns [8*co, 8*co+8)

    const float4* xg4 = reinterpret_cast<const float4*>(x + (size_t)node * (F_IN * PERIODS));

    float acc[8][PERIODS];
    #pragma unroll
    for (int c = 0; c < 8; ++c)
        #pragma unroll
        for (int p = 0; p < PERIODS; ++p) acc[c][p] = 0.f;

    for (int f = 0; f < F_IN; ++f) {
        float4 xa = xg4[f * 3 + 0];
        float4 xb = xg4[f * 3 + 1];
        float4 xc = xg4[f * 3 + 2];
        float4 m0 = *reinterpret_cast<const float4*>(&sM[f * 64 + co * 8]);
        float4 m1 = *reinterpret_cast<const float4*>(&sM[f * 64 + co * 8 + 4]);
        float xv[PERIODS] = {xa.x, xa.y, xa.z, xa.w,
                             xb.x, xb.y, xb.z, xb.w,
                             xc.x, xc.y, xc.z, xc.w};
        float mm[8] = {m0.x, m0.y, m0.z, m0.w, m1.x, m1.y, m1.z, m1.w};
        #pragma unroll
        for (int c = 0; c < 8; ++c)
            #pragma unroll
            for (int p = 0; p < PERIODS; ++p)
                acc[c][p] = fmaf(mm[c], xv[p], acc[c][p]);
    }

    __half* un = U + (size_t)node * 768 + co * 8;
    #pragma unroll
    for (int p = 0; p < PERIODS; ++p) {
        union { uint4 u; __half2 h[4]; } r;
        r.h[0] = __floats2half2_rn(acc[0][p], acc[1][p]);
        r.h[1] = __floats2half2_rn(acc[2][p], acc[3][p]);
        r.h[2] = __floats2half2_rn(acc[4][p], acc[5][p]);
        r.h[3] = __floats2half2_rn(acc[6][p], acc[7][p]);
        *reinterpret_cast<uint4*>(un + p * 64) = r.u;
    }
}

// ---------------- fused aggregate + TGCN cell + attention sum + head
// block = 192 threads, one node per block; thread t owns halves [4t, 4t+4)
__global__ void k_agg(const __half* __restrict__ U, const int* __restrict__ rp,
                      const int* __restrict__ srcIdx, const float* __restrict__ dis,
                      const float* __restrict__ cc, const float* __restrict__ probs,
                      const float* __restrict__ Wlin, const float* __restrict__ blin,
                      float* __restrict__ out) {
    int n = blockIdx.x;
    int t = threadIdx.x;          // 0..191
    float dn = dis[n];

    float a0, a1, a2, a3;
    {   // self-loop: weight dis[n]^2
        union { uint2 u; __half2 h[2]; } r;
        r.u = reinterpret_cast<const uint2*>(U + (size_t)n * 768)[t];
        float2 f0 = __half22float2(r.h[0]);
        float2 f1 = __half22float2(r.h[1]);
        float w = dn * dn;
        a0 = w * f0.x; a1 = w * f0.y; a2 = w * f1.x; a3 = w * f1.y;
    }
    int beg = rp[n], end = rp[n + 1];
    int e = beg;
    for (; e + 3 < end; e += 4) {          // unroll x4: 4 gathers in flight
        int s0 = srcIdx[e], s1 = srcIdx[e + 1], s2 = srcIdx[e + 2], s3 = srcIdx[e + 3];
        float w0 = dis[s0] * dn, w1 = dis[s1] * dn, w2 = dis[s2] * dn, w3 = dis[s3] * dn;
        union { uint2 u; __half2 h[2]; } r0, r1, r2, r3;
        r0.u = reinterpret_cast<const uint2*>(U + (size_t)s0 * 768)[t];
        r1.u = reinterpret_cast<const uint2*>(U + (size_t)s1 * 768)[t];
        r2.u = reinterpret_cast<const uint2*>(U + (size_t)s2 * 768)[t];
        r3.u = reinterpret_cast<const uint2*>(U + (size_t)s3 * 768)[t];
        float2 f0, f1;
        f0 = __half22float2(r0.h[0]); f1 = __half22float2(r0.h[1]);
        a0 += w0 * f0.x; a1 += w0 * f0.y; a2 += w0 * f1.x; a3 += w0 * f1.y;
        f0 = __half22float2(r1.h[0]); f1 = __half22float2(r1.h[1]);
        a0 += w1 * f0.x; a1 += w1 * f0.y; a2 += w1 * f1.x; a3 += w1 * f1.y;
        f0 = __half22float2(r2.h[0]); f1 = __half22float2(r2.h[1]);
        a0 += w2 * f0.x; a1 += w2 * f0.y; a2 += w2 * f1.x; a3 += w2 * f1.y;
        f0 = __half22float2(r3.h[0]); f1 = __half22float2(r3.h[1]);
        a0 += w3 * f0.x; a1 += w3 * f0.y; a2 += w3 * f1.x; a3 += w3 * f1.y;
    }
    for (; e < end; ++e) {
        int s = srcIdx[e];
        float w = dis[s] * dn;
        union { uint2 u; __half2 h[2]; } r;
        r.u = reinterpret_cast<const uint2*>(U + (size_t)s * 768)[t];
        float2 f0 = __half22float2(r.h[0]);
        float2 f1 = __half22float2(r.h[1]);
        a0 += w * f0.x; a1 += w * f0.y; a2 += w * f1.x; a3 += w * f1.y;
    }

    __shared__ float sacc[768];
    __shared__ float sterm[PERIODS * 32];
    __shared__ float shf[32];
    sacc[4 * t + 0] = a0; sacc[4 * t + 1] = a1;
    sacc[4 * t + 2] = a2; sacc[4 * t + 3] = a3;
    __syncthreads();

    for (int w2 = t; w2 < PERIODS * 32; w2 += 192) {
        int p = w2 >> 5, c = w2 & 31;
        float z = sacc[p * 64 + c]      + cc[c];
        float h = sacc[p * 64 + 32 + c] + cc[32 + c];
        float zs = 1.f / (1.f + __expf(-z));
        sterm[w2] = probs[p] * (1.f - zs) * tanhf(h);
    }
    __syncthreads();

    if (t < 32) {
        float s = 0.f;
        #pragma unroll
        for (int p = 0; p < PERIODS; ++p) s += sterm[p * 32 + t];
        shf[t] = fmaxf(s, 0.f);
    }
    __syncthreads();

    if (t < PERIODS) {
        float o = blin[t];
        #pragma unroll 8
        for (int c = 0; c < OUT; ++c) o += shf[c] * Wlin[c * PERIODS + t];
        out[(size_t)n * PERIODS + t] = o;
    }
}

extern "C" void kernel_launch(void* const* d_in, const int* in_sizes, int n_in,
                              void* d_out, int out_size, void* d_ws, size_t ws_size,
                              hipStream_t stream) {
    const float* x    = (const float*)d_in[0];
    const int*   ei   = (const int*)d_in[1];
    const float* Wz   = (const float*)d_in[2];
    const float* bz   = (const float*)d_in[3];
    const float* Lz   = (const float*)d_in[4];
    const float* lbz  = (const float*)d_in[5];
    const float* Wh   = (const float*)d_in[6];
    const float* bh   = (const float*)d_in[7];
    const float* Lh   = (const float*)d_in[8];
    const float* lbh  = (const float*)d_in[9];
    const float* att  = (const float*)d_in[10];
    const float* Wlin = (const float*)d_in[11];
    const float* blin = (const float*)d_in[12];
    float* out = (float*)d_out;

    char* w = (char*)d_ws;
    size_t off = 0;
    __half* U      = (__half*)(w + off); off += (size_t)N_NODES * 768 * 2; // 153.6 MB
    float*  M      = (float*)(w + off);  off += 128 * 64 * 4;
    float*  cc     = (float*)(w + off);  off += 256;
    float*  probs  = (float*)(w + off);  off += 64;
    float*  dis    = (float*)(w + off);  off += N_NODES * 4;
    int*    cnt    = (int*)(w + off);    off += N_NODES * 4;
    int*    rp     = (int*)(w + off);    off += (N_NODES + 1) * 4 + 12;
    int*    parts  = (int*)(w + off);    off += 2048;
    int*    srcIdx = (int*)(w + off);    off += (size_t)N_EDGES * 4;
    (void)ws_size; (void)in_sizes; (void)n_in; (void)out_size;

    const int SCAN_BLOCKS = (N_NODES + 255) / 256; // 391

    hipMemsetAsync(cnt, 0, N_NODES * 4, stream);

    k_prep<<<1, 256, 0, stream>>>(Wz, bz, Lz, lbz, Wh, bh, Lh, lbh, att, M, cc, probs);
    k_count<<<(N_EDGES + 255) / 256, 256, 0, stream>>>(ei, cnt);
    k_dis<<<SCAN_BLOCKS, 256, 0, stream>>>(cnt, dis);
    k_scan1<<<SCAN_BLOCKS, 256, 0, stream>>>(cnt, rp, parts);
    k_scan2<<<1, 512, 0, stream>>>(parts, SCAN_BLOCKS);
    k_scan3<<<SCAN_BLOCKS, 256, 0, stream>>>(rp, parts);
    k_fill<<<(N_EDGES + 255) / 256, 256, 0, stream>>>(ei, rp, cnt, srcIdx);
    k_proj4<<<N_NODES / 32, 256, 0, stream>>>(x, M, U);
    k_agg<<<N_NODES, 192, 0, stream>>>(U, rp, srcIdx, dis, cc, probs, Wlin, blin, out);
}